// Round 3
// baseline (253.152 us; speedup 1.0000x reference)
//
#include <hip/hip_runtime.h>
#include <stdint.h>

typedef unsigned short u16;
typedef unsigned int   u32;
typedef __bf16 bf16x8 __attribute__((ext_vector_type(8)));
typedef float  f32x4  __attribute__((ext_vector_type(4)));
typedef u32    u32x4  __attribute__((ext_vector_type(4)));

#define L_IN 784
#define KPAD 832
#define KT_N 13

__device__ __forceinline__ u32 f2bf(float f){
    u32 u = __float_as_uint(f);
    return (u + 0x7fffu + ((u >> 16) & 1u)) >> 16;   // RNE truncate to bf16
}
__device__ __forceinline__ float bf2f(u32 s){ return __uint_as_float(s << 16); }

// ---------------------------------------------------------------------------
// K0: W0 [784][128] f32 -> Wt [13][128][64] bf16 (kt-major, col, k-in-tile).
// Zero-pad k >= 784. Lane-contiguous writes; one-time tiny kernel.
// ---------------------------------------------------------------------------
__global__ void prep_w0(const float* __restrict__ W0, u16* __restrict__ Wt){
    int idx = blockIdx.x * 256 + threadIdx.x;        // 13*8192 = 106496 total
    if (idx >= KPAD * 128) return;
    int kin = idx & 63, col = (idx >> 6) & 127, kt = idx >> 13;
    int k = kt * 64 + kin;
    float v = (k < L_IN) ? W0[k * 128 + col] : 0.f;
    Wt[idx] = (u16)f2bf(v);
}

// ---------------------------------------------------------------------------
// K1: x = relu(h @ W0 + b0). Barrier-free, LDS-free MFMA GEMM.
// Each wave owns 32 rows (no cross-wave A reuse -> A direct global->reg).
// B fragments read directly from L2-resident Wt. 1-deep register ping-pong
// prefetch of A keeps HBM loads in flight continuously (no vmcnt(0) drains).
// ---------------------------------------------------------------------------
__global__ __launch_bounds__(256, 2)
void fc_gemm(const float* __restrict__ hG, const u16* __restrict__ Wt,
             const float* __restrict__ b0, u16* __restrict__ xbf, int N){
    const int t    = threadIdx.x;
    const int lane = t & 63;
    const int w    = t >> 6;
    const int gb   = blockIdx.x;
    const int lr   = lane & 15;          // row-within-16 (A) / col-within-16 (B)
    const int lk   = lane >> 4;          // k-slot 0..3 (8 elems each)

    const long rowBase = (long)gb * 128 + w * 32;
    long r0 = rowBase + lr;        if (r0 >= N) r0 = N - 1;   // clamp: OOB rows
    long r1 = rowBase + 16 + lr;   if (r1 >= N) r1 = N - 1;   // compute garbage,
    const float* a0p = hG + r0 * L_IN;                        // store is guarded
    const float* a1p = hG + r1 * L_IN;

    f32x4 acc[2][8];
    #pragma unroll
    for (int i = 0; i < 2; ++i)
        #pragma unroll
        for (int j = 0; j < 8; ++j)
            acc[i][j] = (f32x4)0.f;

    // A prefetch: [mt][kk][half] = 8 float4 = 32 VGPR per buffer.
    f32x4 paA[2][2][2], paB[2][2][2];

    // K-tile 12 covers k=768..831; only k<784 exists. B is zero-padded there,
    // so A values are don't-care — but avoid OOB reads past the buffer end:
    // only (kk==0, lk<2) lanes read (k 768..783); everything else loads 0.
    auto prefA = [&](int ktn, f32x4 (&dst)[2][2][2]){
        #pragma unroll
        for (int mt = 0; mt < 2; ++mt){
            const float* rp = mt ? a1p : a0p;
            #pragma unroll
            for (int kk = 0; kk < 2; ++kk){
                const float* p = rp + ktn * 64 + kk * 32 + lk * 8;
                if (ktn < KT_N - 1 || (kk == 0 && lk < 2)){
                    dst[mt][kk][0] = *(const f32x4*)p;
                    dst[mt][kk][1] = *(const f32x4*)(p + 4);
                } else {
                    dst[mt][kk][0] = (f32x4)0.f;
                    dst[mt][kk][1] = (f32x4)0.f;
                }
            }
        }
    };

    auto body = [&](int kt, f32x4 (&cur)[2][2][2], f32x4 (&nxt)[2][2][2], bool pre){
        // 1. issue next K-tile's A loads (HBM) — consumed next iteration
        if (pre) prefA(kt + 1, nxt);
        // 2. B fragments direct from L2 (col = nt*16+lr, k-chunk = kk*32+lk*8)
        bf16x8 bfr[2][8];
        #pragma unroll
        for (int kk = 0; kk < 2; ++kk)
            #pragma unroll
            for (int nt = 0; nt < 8; ++nt)
                bfr[kk][nt] = *(const bf16x8*)(Wt + kt * 8192 + (nt * 16 + lr) * 64 + kk * 32 + lk * 8);
        // 3. convert this K-tile's A (prefetched last iteration) to bf16 frags
        bf16x8 af[2][2];
        #pragma unroll
        for (int mt = 0; mt < 2; ++mt)
            #pragma unroll
            for (int kk = 0; kk < 2; ++kk){
                bf16x8 r;
                #pragma unroll
                for (int j = 0; j < 4; ++j){
                    r[j]     = (__bf16)cur[mt][kk][0][j];
                    r[4 + j] = (__bf16)cur[mt][kk][1][j];
                }
                af[mt][kk] = r;
            }
        // 4. MFMA
        #pragma unroll
        for (int kk = 0; kk < 2; ++kk)
            #pragma unroll
            for (int mt = 0; mt < 2; ++mt)
                #pragma unroll
                for (int nt = 0; nt < 8; ++nt)
                    acc[mt][nt] = __builtin_amdgcn_mfma_f32_16x16x32_bf16(af[mt][kk], bfr[kk][nt], acc[mt][nt], 0, 0, 0);
    };

    prefA(0, paA);
    #pragma unroll
    for (int kt2 = 0; kt2 < (KT_N - 1) / 2; ++kt2){
        body(2 * kt2,     paA, paB, true);
        body(2 * kt2 + 1, paB, paA, true);
    }
    body(KT_N - 1, paA, paB, false);

    // ---- epilogue: + bias, relu, store bf16 ----
    #pragma unroll
    for (int nt = 0; nt < 8; ++nt){
        int col = nt * 16 + lr;
        float bias = b0[col];
        #pragma unroll
        for (int mt = 0; mt < 2; ++mt){
            long row0 = rowBase + mt * 16 + lk * 4;
            #pragma unroll
            for (int r = 0; r < 4; ++r){
                long row = row0 + r;
                if (row < (long)N){
                    float v = acc[mt][nt][r] + bias;
                    v = v > 0.f ? v : 0.f;
                    xbf[(size_t)row * 128 + col] = (u16)f2bf(v);
                }
            }
        }
    }
}

// ---------------------------------------------------------------------------
// K2: gated attention logits + exp + block pooling partials.
// ---------------------------------------------------------------------------
__global__ __launch_bounds__(256, 2)
void attn_pool(const u16* __restrict__ xbf,
               const float* __restrict__ Wa, const float* __restrict__ ba,
               const float* __restrict__ Wb, const float* __restrict__ bb,
               const float* __restrict__ Wc, const float* __restrict__ bc,
               float* __restrict__ partials, float* __restrict__ psum, int N){
    __shared__ __align__(16) float Wa_s[4096], Wb_s[4096];
    __shared__ float ba_s[64], bb_s[64], Wc_s[64], bc_s[2];
    __shared__ float eA[128][2];

    const int t  = threadIdx.x;
    const int gb = blockIdx.x;

    for (int i = t; i < 4096; i += 256){ Wa_s[i] = Wa[i]; Wb_s[i] = Wb[i]; }
    if (t < 64){ ba_s[t] = ba[t]; bb_s[t] = bb[t]; Wc_s[t] = Wc[t]; }
    if (t < 2)  bc_s[t] = bc[t];
    __syncthreads();

    // ---- phase 1: attention logit per (instance, head) ----
    {
        const int inst = t & 127, hh = t >> 7;
        const long gi = (long)gb * 128 + inst;
        float aa[32], ag[32];
        #pragma unroll
        for (int d = 0; d < 32; ++d){ aa[d] = ba_s[hh*32+d]; ag[d] = bb_s[hh*32+d]; }
        const float* wa = &Wa_s[hh * 2048];
        const float* wb = &Wb_s[hh * 2048];
        const u16*   xp = xbf + gi * 128 + hh * 64;
        for (int c = 0; c < 8; ++c){
            u32x4 xc = *(const u32x4*)(xp + c * 8);
            #pragma unroll
            for (int s8 = 0; s8 < 8; ++s8){
                u32 uw = xc[s8 >> 1];
                float xv = bf2f((s8 & 1) ? (uw >> 16) : (uw & 0xffffu));
                const int s = c * 8 + s8;
                #pragma unroll
                for (int q = 0; q < 8; ++q){
                    f32x4 w4 = *(const f32x4*)(wa + s * 32 + q * 4);
                    f32x4 v4 = *(const f32x4*)(wb + s * 32 + q * 4);
                    aa[q*4+0] += xv * w4[0]; aa[q*4+1] += xv * w4[1];
                    aa[q*4+2] += xv * w4[2]; aa[q*4+3] += xv * w4[3];
                    ag[q*4+0] += xv * v4[0]; ag[q*4+1] += xv * v4[1];
                    ag[q*4+2] += xv * v4[2]; ag[q*4+3] += xv * v4[3];
                }
            }
        }
        float A = bc_s[hh];
        #pragma unroll
        for (int d = 0; d < 32; ++d){
            float av = tanhf(aa[d]);
            float gv = 1.f / (1.f + expf(-ag[d]));
            A += av * gv * Wc_s[hh*32+d];
        }
        // exp without max-subtraction: |A| <= sum|Wc|+|bc| (~7), safe in f32.
        eA[inst][hh] = (gi < (long)N) ? expf(A) : 0.f;
    }
    __syncthreads();

    if (t < 2){
        float s = 0.f;
        for (int i = 0; i < 128; ++i) s += eA[i][t];
        psum[gb * 2 + t] = s;
    }

    // ---- phase 2: pooling partials sum(e * x) over this block's instances ----
    {
        const int ui = t >> 2, q = t & 3;   // ui: uint channel 0..63, q: quarter
        const int hh = ui >> 5;
        float p0 = 0.f, p1 = 0.f;
        #pragma unroll 4
        for (int i = 0; i < 32; ++i){
            const int inst = q * 32 + i;
            u32 u = *(const u32*)(xbf + ((long)gb * 128 + inst) * 128 + ui * 2);
            float e = eA[inst][hh];
            p0 += e * bf2f(u & 0xffffu);
            p1 += e * bf2f(u >> 16);
        }
        partials[(size_t)gb * 512 + ui * 8 + 0 + q] = p0;
        partials[(size_t)gb * 512 + ui * 8 + 4 + q] = p1;
    }
}

// ---------------------------------------------------------------------------
// K3a: first-stage reduction over the nb dimension. 128 blocks x 256 threads.
// ---------------------------------------------------------------------------
__global__ __launch_bounds__(256)
void reduce1(const float* __restrict__ partials, const float* __restrict__ psum,
             float* __restrict__ red, int nb){
    const int b = blockIdx.x, t = threadIdx.x;
    float a0 = 0.f, a1 = 0.f;
    for (int r = b; r < nb; r += 128){
        a0 += partials[(size_t)r * 512 + t];
        a1 += partials[(size_t)r * 512 + t + 256];
    }
    red[b * 520 + t]       = a0;
    red[b * 520 + t + 256] = a1;
    if (t < 2){
        float s = 0.f;
        for (int r = b; r < nb; r += 128) s += psum[r * 2 + t];
        red[b * 520 + 512 + t] = s;
    }
}

// ---------------------------------------------------------------------------
// K3b: combine 128 reduced rows (f64), M, logits, sigmoid, Y_hat. One block.
// ---------------------------------------------------------------------------
__global__ __launch_bounds__(256)
void finalize2(const float* __restrict__ red, const float* __restrict__ Wcls,
               const float* __restrict__ bcls, float* __restrict__ out){
    __shared__ double colD[512];
    __shared__ double den[2];
    __shared__ float  M_s[128];
    const int t = threadIdx.x;
    double d0 = 0.0, d1 = 0.0;
    for (int r = 0; r < 128; ++r){
        d0 += (double)red[r * 520 + t];
        d1 += (double)red[r * 520 + t + 256];
    }
    colD[t]       = d0;
    colD[t + 256] = d1;
    if (t < 2){
        double s = 0.0;
        for (int r = 0; r < 128; ++r) s += (double)red[r * 520 + 512 + t];
        den[t] = s;
    }
    __syncthreads();
    if (t < 128){
        const double* p = &colD[(t >> 1) * 8 + (t & 1) * 4];
        M_s[t] = (float)((p[0] + p[1] + p[2] + p[3]) / den[t >> 6]);
    }
    __syncthreads();
    if (t == 0){
        double lg = (double)bcls[0];
        for (int c = 0; c < 128; ++c) lg += (double)M_s[c] * (double)Wcls[c];
        float pr = (float)(1.0 / (1.0 + exp(-lg)));
        out[0] = pr;
        out[1] = (lg >= 0.0) ? 1.f : 0.f;
    }
}

// ---------------------------------------------------------------------------
extern "C" void kernel_launch(void* const* d_in, const int* in_sizes, int n_in,
                              void* d_out, int out_size, void* d_ws, size_t ws_size,
                              hipStream_t stream){
    const float* hG   = (const float*)d_in[0];
    const float* W0   = (const float*)d_in[1];
    const float* b0   = (const float*)d_in[2];
    const float* Wa   = (const float*)d_in[3];
    const float* ba   = (const float*)d_in[4];
    const float* Wb   = (const float*)d_in[5];
    const float* bb   = (const float*)d_in[6];
    const float* Wc   = (const float*)d_in[7];
    const float* bc   = (const float*)d_in[8];
    const float* Wcls = (const float*)d_in[9];
    const float* bcls = (const float*)d_in[10];

    const int N  = in_sizes[0] / L_IN;
    const int nb = (N + 127) / 128;

    char* ws = (char*)d_ws;
    u16* Wt   = (u16*)ws;                                  // 13*8192*2 = 212992 B
    u16* xbf  = (u16*)(ws + 262144);                       // nb*128*128*2 B
    size_t xbytes = (size_t)nb * 128 * 128 * 2;
    size_t poff   = 262144 + ((xbytes + 4095) & ~(size_t)4095);
    float* partials = (float*)(ws + poff);                 // nb*512 f32
    float* psum     = partials + (size_t)nb * 512;         // nb*2 f32
    size_t roff     = poff + (((size_t)nb * 514 * 4 + 4095) & ~(size_t)4095);
    float* red      = (float*)(ws + roff);                 // 128*520 f32 = 266 KB

    prep_w0  <<<(KPAD * 128 + 255) / 256, 256, 0, stream>>>(W0, Wt);
    fc_gemm  <<<nb, 256, 0, stream>>>(hG, Wt, b0, xbf, N);
    attn_pool<<<nb, 256, 0, stream>>>(xbf, Wa, ba, Wb, bb, Wc, bc, partials, psum, N);
    reduce1  <<<128, 256, 0, stream>>>(partials, psum, red, nb);
    finalize2<<<1, 256, 0, stream>>>(red, Wcls, bcls, (float*)d_out);
}